// Round 1
// baseline (685.677 us; speedup 1.0000x reference)
//
#include <hip/hip_runtime.h>

// AreaSelfAttention fused kernel for MI355X (gfx950).
// x:(4,256,252,252) fp32 -> pad to 256x256 -> 8x8 windows -> per-window
// q,k(32xP),v(256xP) 1x1 convs, S=q^T k, softmax rows, O=V P^T, out=gamma*O+x.
// One workgroup (4 waves) per window; 4096 windows.
// R3: occupancy 3->4 blocks/CU (LDS 53248->40960 via XOR-swizzled strides +
// ps aliased onto dead qs/ks), V GEMM computed TRANSPOSED so both the V LDS
// write and the O-phase A-operand are contiguous vector ops (removes the 64x
// ds_read_u16 8-way-conflicted gather), phase-1 LDS writes vectorized to b64.

#define HH 252
#define WW 252
#define CC 256
#define HW (HH * WW)

typedef __attribute__((ext_vector_type(8))) short bf8;     // 8 bf16 in 4 VGPRs
typedef __attribute__((ext_vector_type(4))) float f32x4;

__device__ __forceinline__ short f2bf(float f) {
    union { float f; unsigned u; } v; v.f = f;
    unsigned u = v.u;
    unsigned r = (u + 0x7fffu + ((u >> 16) & 1u)) >> 16;   // RNE
    return (short)r;
}

__device__ __forceinline__ unsigned pk2(float a, float b) {
    return (unsigned)(unsigned short)f2bf(a) |
           ((unsigned)(unsigned short)f2bf(b) << 16);
}

// ---- LDS address maps (short indices). All XOR-swizzled on 8-short (16B)
// slots so that the l15-varying MFMA fragment reads spread uniformly over the
// 8 16B bank-groups (l15&7 XORs into the slot index), and writes stay b64-
// contiguous (slot constant within each 4-short pack).
__device__ __forceinline__ int xaddr(int p, int c) {   // X^T [p=64][c=256]
    int slot = (c >> 3) ^ ((p & 7) ^ ((p >> 3) & 7));  // low 3 bits flipped
    return p * 256 + (slot << 3) + (c & 7);
}
__device__ __forceinline__ int vaddr(int c, int p) {   // V [c=256][p=64]
    int slot = ((p >> 3) ^ (c & 7)) & 7;
    return c * 64 + (slot << 3) + (p & 7);
}
__device__ __forceinline__ int qaddr(int p, int cr) {  // q^T/k^T [p=64][cr=32]
    int slot = ((cr >> 3) ^ (p & 3)) & 3;
    return p * 32 + (slot << 3) + (cr & 7);
}
__device__ __forceinline__ int paddr(int i, int j) {   // P [i=64][j=64]
    int slot = ((j >> 3) ^ (i & 7)) & 7;
    return i * 64 + (slot << 3) + (j & 7);
}

// Convert Wq (32x256), Wk (32x256), Wv (256x256) fp32 row-major [o][c] into
// bf16 laid out in MFMA A-fragment order:
//   frag (mt,kt), lane l, elem j  ->  W[mt*16 + (l&15)][kt*32 + (l>>4)*8 + j]
// stored at ((mt*8+kt)*64 + l)*8 + j. WqF at 0, WkF at 8192, WvF at 16384.
// NOTE: the B-fragment of W^T has IDENTICAL per-lane indexing (m-tile -> n-
// tile), so the same data serves the transposed V GEMM unchanged.
__global__ __launch_bounds__(256) void prep_weights(
        const float* __restrict__ Wq, const float* __restrict__ Wk,
        const float* __restrict__ Wv, short* __restrict__ wf) {
    int t = blockIdx.x * 256 + threadIdx.x;
    if (t >= 81920) return;
    const float* W; int off, base;
    if (t < 8192)       { W = Wq; off = t;         base = 0; }
    else if (t < 16384) { W = Wk; off = t - 8192;  base = 8192; }
    else                { W = Wv; off = t - 16384; base = 16384; }
    int j = off & 7, l = (off >> 3) & 63, tile = off >> 9;
    int kt = tile & 7, mt = tile >> 3;
    int m = mt * 16 + (l & 15);
    int k = kt * 32 + ((l >> 4) * 8) + j;
    wf[base + off] = f2bf(W[m * 256 + k]);
}

__global__ __launch_bounds__(256, 4) void area_attn(
        const float* __restrict__ x, const short* __restrict__ wf,
        const float* __restrict__ bq, const float* __restrict__ bk,
        const float* __restrict__ bv, const float* __restrict__ gamma,
        float* __restrict__ out) {
    // LDS = 32768 + 8192 = 40960 B -> exactly 4 workgroups / CU (160 KiB).
    __shared__ short xs[16384];   // X^T[p][c] (phases 1-2), then V[c][p]
    __shared__ short qk[4096];    // qs[0:2048] + ks[2048:4096]; ps aliases all

    const int tid  = threadIdx.x;
    const int lane = tid & 63, wv = tid >> 6;
    const int l15  = lane & 15, quad = lane >> 4;

    // XCD-aware swizzle: xcd = bid&7 (HW round-robin). Each XCD owns whole
    // window-rows; nx is the innermost sweep per XCD (L2 line sharing).
    const int bid  = blockIdx.x;
    const int xcd  = bid & 7;
    const int jb   = bid >> 3;          // 0..511
    const int nx   = jb & 31;
    const int grow = (jb >> 5) * 8 + xcd; // 0..127 global window-row id
    const int bimg = grow >> 5;
    const int ny   = grow & 31;
    const int hb = ny * 8, wb = nx * 8;
    const float* xb = x   + (size_t)bimg * CC * HW;
    float*       ob = out + (size_t)bimg * CC * HW;

    const f32x4 zero4 = {0.f, 0.f, 0.f, 0.f};

    // ---- phase 1: global x -> LDS bf16 X^T[p][c], zero-padded outside image.
    // Each thread: 4 iterations x (4 float4 channel loads -> 4 b64 packed
    // writes). 252 = 248+4 so edge float4s are fully OOB (never partial).
    {
        int s = tid & 15, cg = tid >> 4;            // s: position group, cg: c/4
        int h = hb + (s >> 1), w0 = wb + (s & 1) * 4;
        bool inb = (h < HH) && (w0 < WW);
        const float* src = xb + (size_t)h * WW + w0;
        int p0 = s * 4;
        #pragma unroll
        for (int it = 0; it < 4; ++it) {
            int c0 = it * 64 + cg * 4;
            float4 f[4];
            #pragma unroll
            for (int k = 0; k < 4; ++k) {
                if (inb) f[k] = *reinterpret_cast<const float4*>(src + (size_t)(c0 + k) * HW);
                else     f[k] = make_float4(0.f, 0.f, 0.f, 0.f);
            }
            #pragma unroll
            for (int i = 0; i < 4; ++i) {
                uint2 w2;
                w2.x = pk2(((const float*)&f[0])[i], ((const float*)&f[1])[i]);
                w2.y = pk2(((const float*)&f[2])[i], ((const float*)&f[3])[i]);
                *reinterpret_cast<uint2*>(&xs[xaddr(p0 + i, c0)]) = w2;
            }
        }
    }
    __syncthreads();

    // ---- phase 2 (fused): one sweep over X fragments feeds BOTH the Q/K
    // GEMM (waves 0,1 -> Q; 2,3 -> K; X as B-operand) and the transposed
    // V GEMM  V^T[p][c] = X^T[p][cin] * Wv^T[cin][c]  (X as A-operand).
    const bool isK = (wv >> 1) != 0;
    const int mt = wv & 1;
    f32x4 qacc[4];
    #pragma unroll
    for (int nt = 0; nt < 4; ++nt) qacc[nt] = zero4;
    f32x4 vacc[4][4];                       // [p-tile][c-tile within wave]
    #pragma unroll
    for (int t = 0; t < 4; ++t)
        #pragma unroll
        for (int ni = 0; ni < 4; ++ni) vacc[t][ni] = zero4;
    {
        const short* WFqk = wf + (isK ? 8192 : 0);
        #pragma unroll
        for (int kt = 0; kt < 8; ++kt) {
            bf8 xfr[4];
            #pragma unroll
            for (int t = 0; t < 4; ++t)
                xfr[t] = *reinterpret_cast<const bf8*>(
                    &xs[xaddr(t * 16 + l15, kt * 32 + quad * 8)]);
            bf8 aw = *reinterpret_cast<const bf8*>(
                WFqk + ((mt * 8 + kt) * 64 + lane) * 8);
            #pragma unroll
            for (int nt = 0; nt < 4; ++nt)
                qacc[nt] = __builtin_amdgcn_mfma_f32_16x16x32_bf16(
                    aw, xfr[nt], qacc[nt], 0, 0, 0);
            #pragma unroll
            for (int ni = 0; ni < 4; ++ni) {
                bf8 bw = *reinterpret_cast<const bf8*>(
                    wf + 16384 + (((wv * 4 + ni) * 8 + kt) * 64 + lane) * 8);
                #pragma unroll
                for (int t = 0; t < 4; ++t)
                    vacc[t][ni] = __builtin_amdgcn_mfma_f32_16x16x32_bf16(
                        xfr[t], bw, vacc[t][ni], 0, 0, 0);
            }
        }
    }
    // q^T/k^T (+bias, bf16) -> LDS [pos][cr]
    {
        int cb = mt * 16 + quad * 4;
        const float* bias = isK ? bk : bq;
        float bi0 = bias[cb + 0], bi1 = bias[cb + 1];
        float bi2 = bias[cb + 2], bi3 = bias[cb + 3];
        short* dst = isK ? (qk + 2048) : qk;
        #pragma unroll
        for (int nt = 0; nt < 4; ++nt) {
            int pos = nt * 16 + l15;
            uint2 w2;
            w2.x = pk2(qacc[nt][0] + bi0, qacc[nt][1] + bi1);
            w2.y = pk2(qacc[nt][2] + bi2, qacc[nt][3] + bi3);
            *reinterpret_cast<uint2*>(&dst[qaddr(pos, cb)]) = w2;
        }
    }
    __syncthreads();   // all X reads done; qs/ks visible to everyone

    // ---- write V (+bias, bf16) into xs as V[c][p]: lane holds 4 consecutive
    // p for one c -> contiguous b64 writes (this is the transposed-GEMM win).
    #pragma unroll
    for (int ni = 0; ni < 4; ++ni) {
        int c = wv * 64 + ni * 16 + l15;
        float bvc = bv[c];
        #pragma unroll
        for (int t = 0; t < 4; ++t) {
            int p = t * 16 + quad * 4;
            uint2 w2;
            w2.x = pk2(vacc[t][ni][0] + bvc, vacc[t][ni][1] + bvc);
            w2.y = pk2(vacc[t][ni][2] + bvc, vacc[t][ni][3] + bvc);
            *reinterpret_cast<uint2*>(&xs[vaddr(c, p)]) = w2;
        }
    }
    // S-phase operands must be read BEFORE ps overwrites qs/ks (aliased).
    bf8 aq = *reinterpret_cast<const bf8*>(&qk[qaddr(wv * 16 + l15, quad * 8)]);
    bf8 kb8[4];
    #pragma unroll
    for (int nt = 0; nt < 4; ++nt)
        kb8[nt] = *reinterpret_cast<const bf8*>(
            &qk[2048 + qaddr(nt * 16 + l15, quad * 8)]);
    __syncthreads();   // qs/ks reads done -> ps may alias; V visible

    // ---- S = q^T k (M=i, N=j, K=32), softmax rows, P -> LDS bf16 (in qk)
    {
        f32x4 sacc[4];
        #pragma unroll
        for (int nt = 0; nt < 4; ++nt)
            sacc[nt] = __builtin_amdgcn_mfma_f32_16x16x32_bf16(
                aq, kb8[nt], zero4, 0, 0, 0);
        #pragma unroll
        for (int r = 0; r < 4; ++r) {
            float mx = fmaxf(fmaxf(sacc[0][r], sacc[1][r]),
                             fmaxf(sacc[2][r], sacc[3][r]));
            for (int m = 1; m < 16; m <<= 1) mx = fmaxf(mx, __shfl_xor(mx, m, 64));
            float e0 = __expf(sacc[0][r] - mx);
            float e1 = __expf(sacc[1][r] - mx);
            float e2 = __expf(sacc[2][r] - mx);
            float e3 = __expf(sacc[3][r] - mx);
            float sum = e0 + e1 + e2 + e3;
            for (int m = 1; m < 16; m <<= 1) sum += __shfl_xor(sum, m, 64);
            float inv = 1.f / sum;
            int i = wv * 16 + quad * 4 + r;
            qk[paddr(i,  0 + l15)] = f2bf(e0 * inv);
            qk[paddr(i, 16 + l15)] = f2bf(e1 * inv);
            qk[paddr(i, 32 + l15)] = f2bf(e2 * inv);
            qk[paddr(i, 48 + l15)] = f2bf(e3 * inv);
        }
    }
    __syncthreads();   // V + P ready

    // ---- O = V P^T (M=c 256, N=i 64, K=j 64). wave w owns c in [64w,64w+64).
    // A-operand is now a contiguous b128 read from V[c][p] (no scalar gather).
    f32x4 oacc[4][4];
    #pragma unroll
    for (int mi = 0; mi < 4; ++mi)
        #pragma unroll
        for (int nt = 0; nt < 4; ++nt) oacc[mi][nt] = zero4;
    #pragma unroll
    for (int kt = 0; kt < 2; ++kt) {
        bf8 av[4], bp[4];
        #pragma unroll
        for (int mi = 0; mi < 4; ++mi)
            av[mi] = *reinterpret_cast<const bf8*>(
                &xs[vaddr((wv * 4 + mi) * 16 + l15, kt * 32 + quad * 8)]);
        #pragma unroll
        for (int nt = 0; nt < 4; ++nt)
            bp[nt] = *reinterpret_cast<const bf8*>(
                &qk[paddr(nt * 16 + l15, kt * 32 + quad * 8)]);
        #pragma unroll
        for (int nt = 0; nt < 4; ++nt)
            #pragma unroll
            for (int mi = 0; mi < 4; ++mi)
                oacc[mi][nt] = __builtin_amdgcn_mfma_f32_16x16x32_bf16(
                    av[mi], bp[nt], oacc[mi][nt], 0, 0, 0);
    }

    // ---- epilogue: out = gamma*O + x on the valid 252x252 crop
    float g = gamma[0];
    #pragma unroll
    for (int nt = 0; nt < 4; ++nt) {
        int pos = nt * 16 + l15;
        int h = hb + (pos >> 3), w = wb + (pos & 7);
        if (h < HH && w < WW) {
            size_t idx = (size_t)h * WW + w;
            #pragma unroll
            for (int mi = 0; mi < 4; ++mi) {
                int c0 = (wv * 4 + mi) * 16 + quad * 4;
                #pragma unroll
                for (int r = 0; r < 4; ++r) {
                    size_t o = (size_t)(c0 + r) * HW + idx;
                    ob[o] = g * oacc[mi][nt][r] + xb[o];
                }
            }
        }
    }
}

extern "C" void kernel_launch(void* const* d_in, const int* in_sizes, int n_in,
                              void* d_out, int out_size, void* d_ws, size_t ws_size,
                              hipStream_t stream) {
    const float* x  = (const float*)d_in[0];
    const float* Wq = (const float*)d_in[1];
    const float* bq = (const float*)d_in[2];
    const float* Wk = (const float*)d_in[3];
    const float* bk = (const float*)d_in[4];
    const float* Wv = (const float*)d_in[5];
    const float* bv = (const float*)d_in[6];
    const float* gm = (const float*)d_in[7];
    short* wf = (short*)d_ws;   // 163840 B of bf16 weight fragments

    prep_weights<<<320, 256, 0, stream>>>(Wq, Wk, Wv, wf);
    area_attn<<<4096, 256, 0, stream>>>(x, wf, bq, bk, bv, gm, (float*)d_out);
}

// Round 2
// 643.591 us; speedup vs baseline: 1.0654x; 1.0654x over previous
//
#include <hip/hip_runtime.h>

// AreaSelfAttention fused kernel for MI355X (gfx950).
// x:(4,256,252,252) fp32 -> pad to 256x256 -> 8x8 windows -> per-window
// q,k(32xP),v(256xP) 1x1 convs, S=q^T k, softmax rows, O=V P^T, out=gamma*O+x.
// One workgroup (4 waves) per window; 4096 windows.
// R4: R3 regressed because the FUSED Q/K+V sweep held ~120 live regs under a
// 128-reg budget (launch_bounds(256,4) -> 4 waves/SIMD) and spilled to
// scratch (+650 MB HBM traffic, VGPR_Count pinned at 64). Un-fuse phase 2:
// 2a Q/K (16 acc) then 2b V (64 acc) so peak liveness fits the budget with
// no scratch. Keeps: 40960 B LDS -> 4 blocks/CU, XOR-swizzled conflict-free
// LDS maps, transposed V GEMM (contiguous V write + O-phase b128 A-reads),
// vectorized phase-1 staging, ps aliased onto dead qs/ks.

#define HH 252
#define WW 252
#define CC 256
#define HW (HH * WW)

typedef __attribute__((ext_vector_type(8))) short bf8;     // 8 bf16 in 4 VGPRs
typedef __attribute__((ext_vector_type(4))) float f32x4;

__device__ __forceinline__ short f2bf(float f) {
    union { float f; unsigned u; } v; v.f = f;
    unsigned u = v.u;
    unsigned r = (u + 0x7fffu + ((u >> 16) & 1u)) >> 16;   // RNE
    return (short)r;
}

__device__ __forceinline__ unsigned pk2(float a, float b) {
    return (unsigned)(unsigned short)f2bf(a) |
           ((unsigned)(unsigned short)f2bf(b) << 16);
}

// ---- LDS address maps (short indices). All XOR-swizzled on 8-short (16B)
// slots so that the l15-varying MFMA fragment reads spread uniformly over the
// 8 16B bank-groups, and writes stay b64-contiguous.
__device__ __forceinline__ int xaddr(int p, int c) {   // X^T [p=64][c=256]
    int slot = (c >> 3) ^ ((p & 7) ^ ((p >> 3) & 7));
    return p * 256 + (slot << 3) + (c & 7);
}
__device__ __forceinline__ int vaddr(int c, int p) {   // V [c=256][p=64]
    int slot = ((p >> 3) ^ (c & 7)) & 7;
    return c * 64 + (slot << 3) + (p & 7);
}
__device__ __forceinline__ int qaddr(int p, int cr) {  // q^T/k^T [p=64][cr=32]
    int slot = ((cr >> 3) ^ (p & 3)) & 3;
    return p * 32 + (slot << 3) + (cr & 7);
}
__device__ __forceinline__ int paddr(int i, int j) {   // P [i=64][j=64]
    int slot = ((j >> 3) ^ (i & 7)) & 7;
    return i * 64 + (slot << 3) + (j & 7);
}

// Convert Wq (32x256), Wk (32x256), Wv (256x256) fp32 row-major [o][c] into
// bf16 laid out in MFMA A-fragment order:
//   frag (mt,kt), lane l, elem j  ->  W[mt*16 + (l&15)][kt*32 + (l>>4)*8 + j]
// stored at ((mt*8+kt)*64 + l)*8 + j. WqF at 0, WkF at 8192, WvF at 16384.
// The B-fragment of W^T has IDENTICAL per-lane indexing, so the same data
// serves the transposed V GEMM unchanged.
__global__ __launch_bounds__(256) void prep_weights(
        const float* __restrict__ Wq, const float* __restrict__ Wk,
        const float* __restrict__ Wv, short* __restrict__ wf) {
    int t = blockIdx.x * 256 + threadIdx.x;
    if (t >= 81920) return;
    const float* W; int off, base;
    if (t < 8192)       { W = Wq; off = t;         base = 0; }
    else if (t < 16384) { W = Wk; off = t - 8192;  base = 8192; }
    else                { W = Wv; off = t - 16384; base = 16384; }
    int j = off & 7, l = (off >> 3) & 63, tile = off >> 9;
    int kt = tile & 7, mt = tile >> 3;
    int m = mt * 16 + (l & 15);
    int k = kt * 32 + ((l >> 4) * 8) + j;
    wf[base + off] = f2bf(W[m * 256 + k]);
}

__global__ __launch_bounds__(256, 4) void area_attn(
        const float* __restrict__ x, const short* __restrict__ wf,
        const float* __restrict__ bq, const float* __restrict__ bk,
        const float* __restrict__ bv, const float* __restrict__ gamma,
        float* __restrict__ out) {
    // LDS = 32768 + 8192 = 40960 B -> exactly 4 workgroups / CU (160 KiB).
    __shared__ short xs[16384];   // X^T[p][c] (phases 1-2), then V[c][p]
    __shared__ short qk[4096];    // qs[0:2048] + ks[2048:4096]; ps aliases all

    const int tid  = threadIdx.x;
    const int lane = tid & 63, wv = tid >> 6;
    const int l15  = lane & 15, quad = lane >> 4;

    // XCD-aware swizzle: xcd = bid&7 (HW round-robin). Each XCD owns whole
    // window-rows; nx is the innermost sweep per XCD (L2 line sharing).
    const int bid  = blockIdx.x;
    const int xcd  = bid & 7;
    const int jb   = bid >> 3;          // 0..511
    const int nx   = jb & 31;
    const int grow = (jb >> 5) * 8 + xcd; // 0..127 global window-row id
    const int bimg = grow >> 5;
    const int ny   = grow & 31;
    const int hb = ny * 8, wb = nx * 8;
    const float* xb = x   + (size_t)bimg * CC * HW;
    float*       ob = out + (size_t)bimg * CC * HW;

    const f32x4 zero4 = {0.f, 0.f, 0.f, 0.f};

    // ---- phase 1: global x -> LDS bf16 X^T[p][c], zero-padded outside image.
    // Each thread: 4 iterations x (4 float4 channel loads -> 4 b64 packed
    // writes). 252 = 248+4 so edge float4s are fully OOB (never partial).
    {
        int s = tid & 15, cg = tid >> 4;            // s: position group, cg: c/4
        int h = hb + (s >> 1), w0 = wb + (s & 1) * 4;
        bool inb = (h < HH) && (w0 < WW);
        const float* src = xb + (size_t)h * WW + w0;
        int p0 = s * 4;
        #pragma unroll
        for (int it = 0; it < 4; ++it) {
            int c0 = it * 64 + cg * 4;
            float4 f[4];
            #pragma unroll
            for (int k = 0; k < 4; ++k) {
                if (inb) f[k] = *reinterpret_cast<const float4*>(src + (size_t)(c0 + k) * HW);
                else     f[k] = make_float4(0.f, 0.f, 0.f, 0.f);
            }
            #pragma unroll
            for (int i = 0; i < 4; ++i) {
                uint2 w2;
                w2.x = pk2(((const float*)&f[0])[i], ((const float*)&f[1])[i]);
                w2.y = pk2(((const float*)&f[2])[i], ((const float*)&f[3])[i]);
                *reinterpret_cast<uint2*>(&xs[xaddr(p0 + i, c0)]) = w2;
            }
        }
    }
    __syncthreads();

    // ---- phase 2a: Q/K GEMM. waves 0,1 -> Q (mt=wv&1); waves 2,3 -> K.
    // X is the B-operand. Only 16 acc regs live -> no pressure.
    {
        const bool isK = (wv >> 1) != 0;
        const int mt = wv & 1;
        const short* WFqk = wf + (isK ? 8192 : 0);
        f32x4 qacc[4];
        #pragma unroll
        for (int nt = 0; nt < 4; ++nt) qacc[nt] = zero4;
        #pragma unroll
        for (int kt = 0; kt < 8; ++kt) {
            bf8 aw = *reinterpret_cast<const bf8*>(
                WFqk + ((mt * 8 + kt) * 64 + lane) * 8);
            #pragma unroll
            for (int nt = 0; nt < 4; ++nt) {
                bf8 b = *reinterpret_cast<const bf8*>(
                    &xs[xaddr(nt * 16 + l15, kt * 32 + quad * 8)]);
                qacc[nt] = __builtin_amdgcn_mfma_f32_16x16x32_bf16(
                    aw, b, qacc[nt], 0, 0, 0);
            }
        }
        // q^T/k^T (+bias, bf16) -> LDS [pos][cr]
        int cb = mt * 16 + quad * 4;
        const float* bias = isK ? bk : bq;
        float bi0 = bias[cb + 0], bi1 = bias[cb + 1];
        float bi2 = bias[cb + 2], bi3 = bias[cb + 3];
        short* dst = isK ? (qk + 2048) : qk;
        #pragma unroll
        for (int nt = 0; nt < 4; ++nt) {
            int pos = nt * 16 + l15;
            uint2 w2;
            w2.x = pk2(qacc[nt][0] + bi0, qacc[nt][1] + bi1);
            w2.y = pk2(qacc[nt][2] + bi2, qacc[nt][3] + bi3);
            *reinterpret_cast<uint2*>(&dst[qaddr(pos, cb)]) = w2;
        }
    }

    // ---- phase 2b: transposed V GEMM  V^T[p][c] = X^T[p][cin] * Wv^T[cin][c]
    // (X as A-operand). 64 acc regs live, nothing else big -> fits budget.
    f32x4 vacc[4][4];                       // [p-tile][c-tile within wave]
    #pragma unroll
    for (int t = 0; t < 4; ++t)
        #pragma unroll
        for (int ni = 0; ni < 4; ++ni) vacc[t][ni] = zero4;
    {
        #pragma unroll
        for (int kt = 0; kt < 8; ++kt) {
            bf8 xfr[4];
            #pragma unroll
            for (int t = 0; t < 4; ++t)
                xfr[t] = *reinterpret_cast<const bf8*>(
                    &xs[xaddr(t * 16 + l15, kt * 32 + quad * 8)]);
            #pragma unroll
            for (int ni = 0; ni < 4; ++ni) {
                bf8 bw = *reinterpret_cast<const bf8*>(
                    wf + 16384 + (((wv * 4 + ni) * 8 + kt) * 64 + lane) * 8);
                #pragma unroll
                for (int t = 0; t < 4; ++t)
                    vacc[t][ni] = __builtin_amdgcn_mfma_f32_16x16x32_bf16(
                        xfr[t], bw, vacc[t][ni], 0, 0, 0);
            }
        }
    }
    __syncthreads();   // all X reads done; qs/ks visible to everyone

    // ---- write V (+bias, bf16) into xs as V[c][p]: lane holds 4 consecutive
    // p for one c -> contiguous b64 writes (transposed-GEMM win).
    #pragma unroll
    for (int ni = 0; ni < 4; ++ni) {
        int c = wv * 64 + ni * 16 + l15;
        float bvc = bv[c];
        #pragma unroll
        for (int t = 0; t < 4; ++t) {
            int p = t * 16 + quad * 4;
            uint2 w2;
            w2.x = pk2(vacc[t][ni][0] + bvc, vacc[t][ni][1] + bvc);
            w2.y = pk2(vacc[t][ni][2] + bvc, vacc[t][ni][3] + bvc);
            *reinterpret_cast<uint2*>(&xs[vaddr(c, p)]) = w2;
        }
    }
    // S-phase operands must be read BEFORE ps overwrites qs/ks (aliased).
    bf8 aq = *reinterpret_cast<const bf8*>(&qk[qaddr(wv * 16 + l15, quad * 8)]);
    bf8 kb8[4];
    #pragma unroll
    for (int nt = 0; nt < 4; ++nt)
        kb8[nt] = *reinterpret_cast<const bf8*>(
            &qk[2048 + qaddr(nt * 16 + l15, quad * 8)]);
    __syncthreads();   // qs/ks reads done -> ps may alias; V visible

    // ---- S = q^T k (M=i, N=j, K=32), softmax rows, P -> LDS bf16 (in qk)
    {
        f32x4 sacc[4];
        #pragma unroll
        for (int nt = 0; nt < 4; ++nt)
            sacc[nt] = __builtin_amdgcn_mfma_f32_16x16x32_bf16(
                aq, kb8[nt], zero4, 0, 0, 0);
        #pragma unroll
        for (int r = 0; r < 4; ++r) {
            float mx = fmaxf(fmaxf(sacc[0][r], sacc[1][r]),
                             fmaxf(sacc[2][r], sacc[3][r]));
            for (int m = 1; m < 16; m <<= 1) mx = fmaxf(mx, __shfl_xor(mx, m, 64));
            float e0 = __expf(sacc[0][r] - mx);
            float e1 = __expf(sacc[1][r] - mx);
            float e2 = __expf(sacc[2][r] - mx);
            float e3 = __expf(sacc[3][r] - mx);
            float sum = e0 + e1 + e2 + e3;
            for (int m = 1; m < 16; m <<= 1) sum += __shfl_xor(sum, m, 64);
            float inv = 1.f / sum;
            int i = wv * 16 + quad * 4 + r;
            qk[paddr(i,  0 + l15)] = f2bf(e0 * inv);
            qk[paddr(i, 16 + l15)] = f2bf(e1 * inv);
            qk[paddr(i, 32 + l15)] = f2bf(e2 * inv);
            qk[paddr(i, 48 + l15)] = f2bf(e3 * inv);
        }
    }
    __syncthreads();   // V + P ready

    // ---- O = V P^T (M=c 256, N=i 64, K=j 64). wave w owns c in [64w,64w+64).
    // A-operand is a contiguous b128 read from V[c][p] (no scalar gather).
    f32x4 oacc[4][4];
    #pragma unroll
    for (int mi = 0; mi < 4; ++mi)
        #pragma unroll
        for (int nt = 0; nt < 4; ++nt) oacc[mi][nt] = zero4;
    #pragma unroll
    for (int kt = 0; kt < 2; ++kt) {
        bf8 av[4], bp[4];
        #pragma unroll
        for (int mi = 0; mi < 4; ++mi)
            av[mi] = *reinterpret_cast<const bf8*>(
                &xs[vaddr((wv * 4 + mi) * 16 + l15, kt * 32 + quad * 8)]);
        #pragma unroll
        for (int nt = 0; nt < 4; ++nt)
            bp[nt] = *reinterpret_cast<const bf8*>(
                &qk[paddr(nt * 16 + l15, kt * 32 + quad * 8)]);
        #pragma unroll
        for (int nt = 0; nt < 4; ++nt)
            #pragma unroll
            for (int mi = 0; mi < 4; ++mi)
                oacc[mi][nt] = __builtin_amdgcn_mfma_f32_16x16x32_bf16(
                    av[mi], bp[nt], oacc[mi][nt], 0, 0, 0);
    }

    // ---- epilogue: out = gamma*O + x on the valid 252x252 crop
    float g = gamma[0];
    #pragma unroll
    for (int nt = 0; nt < 4; ++nt) {
        int pos = nt * 16 + l15;
        int h = hb + (pos >> 3), w = wb + (pos & 7);
        if (h < HH && w < WW) {
            size_t idx = (size_t)h * WW + w;
            #pragma unroll
            for (int mi = 0; mi < 4; ++mi) {
                int c0 = (wv * 4 + mi) * 16 + quad * 4;
                #pragma unroll
                for (int r = 0; r < 4; ++r) {
                    size_t o = (size_t)(c0 + r) * HW + idx;
                    ob[o] = g * oacc[mi][nt][r] + xb[o];
                }
            }
        }
    }
}

extern "C" void kernel_launch(void* const* d_in, const int* in_sizes, int n_in,
                              void* d_out, int out_size, void* d_ws, size_t ws_size,
                              hipStream_t stream) {
    const float* x  = (const float*)d_in[0];
    const float* Wq = (const float*)d_in[1];
    const float* bq = (const float*)d_in[2];
    const float* Wk = (const float*)d_in[3];
    const float* bk = (const float*)d_in[4];
    const float* Wv = (const float*)d_in[5];
    const float* bv = (const float*)d_in[6];
    const float* gm = (const float*)d_in[7];
    short* wf = (short*)d_ws;   // 163840 B of bf16 weight fragments

    prep_weights<<<320, 256, 0, stream>>>(Wq, Wk, Wv, wf);
    area_attn<<<4096, 256, 0, stream>>>(x, wf, bq, bk, bv, gm, (float*)d_out);
}

// Round 3
// 558.233 us; speedup vs baseline: 1.2283x; 1.1529x over previous
//
#include <hip/hip_runtime.h>

// AreaSelfAttention fused kernel for MI355X (gfx950).
// x:(4,256,252,252) fp32 -> pad to 256x256 -> 8x8 windows -> per-window
// q,k(32xP),v(256xP) 1x1 convs, S=q^T k, softmax rows, O=V P^T, out=gamma*O+x.
// R5: one workgroup (8 waves, 512 thr) per PAIR of horizontally-adjacent
// windows -> every global read/write is a full 64B line (window alone is
// 32B wide; R2->R4 showed the half-line split costs ~250 MB of merge
// failure and the epilogue was 64+64 scalar RMW/thread). Epilogue now
// stages O (f32) in the dead xs buffer and re-emits as coalesced float4
// RMW in two half-passes. Keeps: unfused phase 2 (R4 spill fix), XOR-
// swizzled LDS maps, transposed V GEMM, 2 blocks/CU (81920 B LDS).

#define HH 252
#define WW 252
#define CC 256
#define HW (HH * WW)

typedef __attribute__((ext_vector_type(8))) short bf8;     // 8 bf16 in 4 VGPRs
typedef __attribute__((ext_vector_type(4))) float f32x4;

__device__ __forceinline__ short f2bf(float f) {
    union { float f; unsigned u; } v; v.f = f;
    unsigned u = v.u;
    unsigned r = (u + 0x7fffu + ((u >> 16) & 1u)) >> 16;   // RNE
    return (short)r;
}

__device__ __forceinline__ unsigned pk2(float a, float b) {
    return (unsigned)(unsigned short)f2bf(a) |
           ((unsigned)(unsigned short)f2bf(b) << 16);
}

// ---- LDS address maps (short indices, per 16384-short window region).
// XOR-swizzled on 8-short (16B) slots: MFMA fragment reads spread uniformly
// over the 8 16B bank-groups; writes stay b64-contiguous.
__device__ __forceinline__ int xaddr(int p, int c) {   // X^T [p=64][c=256]
    int slot = (c >> 3) ^ ((p & 7) ^ ((p >> 3) & 7));
    return p * 256 + (slot << 3) + (c & 7);
}
__device__ __forceinline__ int vaddr(int c, int p) {   // V [c=256][p=64]
    int slot = ((p >> 3) ^ (c & 7)) & 7;
    return c * 64 + (slot << 3) + (p & 7);
}
__device__ __forceinline__ int qaddr(int p, int cr) {  // q^T/k^T [p=64][cr=32]
    int slot = ((cr >> 3) ^ (p & 3)) & 3;
    return p * 32 + (slot << 3) + (cr & 7);
}
__device__ __forceinline__ int paddr(int i, int j) {   // P [i=64][j=64]
    int slot = ((j >> 3) ^ (i & 7)) & 7;
    return i * 64 + (slot << 3) + (j & 7);
}
// O staging (f32 [c=128][P=128]); XOR by 16 keeps float4 groups intact and
// puts quad-conflicting writers on the other 16-bank half (2-way = free).
__device__ __forceinline__ int saddr(int c, int P) {
    return c * 128 + (P ^ ((c & 4) << 2));
}

// Convert Wq (32x256), Wk (32x256), Wv (256x256) fp32 row-major [o][c] into
// bf16 laid out in MFMA A-fragment order:
//   frag (mt,kt), lane l, elem j  ->  W[mt*16 + (l&15)][kt*32 + (l>>4)*8 + j]
// stored at ((mt*8+kt)*64 + l)*8 + j. WqF at 0, WkF at 8192, WvF at 16384.
// The B-fragment of W^T has IDENTICAL per-lane indexing, so the same data
// serves the transposed V GEMM unchanged.
__global__ __launch_bounds__(256) void prep_weights(
        const float* __restrict__ Wq, const float* __restrict__ Wk,
        const float* __restrict__ Wv, short* __restrict__ wf) {
    int t = blockIdx.x * 256 + threadIdx.x;
    if (t >= 81920) return;
    const float* W; int off, base;
    if (t < 8192)       { W = Wq; off = t;         base = 0; }
    else if (t < 16384) { W = Wk; off = t - 8192;  base = 8192; }
    else                { W = Wv; off = t - 16384; base = 16384; }
    int j = off & 7, l = (off >> 3) & 63, tile = off >> 9;
    int kt = tile & 7, mt = tile >> 3;
    int m = mt * 16 + (l & 15);
    int k = kt * 32 + ((l >> 4) * 8) + j;
    wf[base + off] = f2bf(W[m * 256 + k]);
}

__global__ __launch_bounds__(512, 4) void area_attn(
        const float* __restrict__ x, const short* __restrict__ wf,
        const float* __restrict__ bq, const float* __restrict__ bk,
        const float* __restrict__ bv, const float* __restrict__ gamma,
        float* __restrict__ out) {
    // LDS = 65536 + 16384 = 81920 B -> exactly 2 workgroups / CU (160 KiB).
    __shared__ __align__(16) short xs[32768]; // per-win 16384: X^T, then V;
                                              // f32 O-stage aliases all 64KB
    __shared__ __align__(16) short qk[8192];  // per-win 4096: qs|ks; ps alias

    const int tid  = threadIdx.x;
    const int lane = tid & 63, wv = tid >> 6;
    const int win  = wv >> 2, wvv = wv & 3;
    const int l15  = lane & 15, quad = lane >> 4;

    // XCD-aware swizzle: xcd = bid&7 (HW round-robin). Each XCD owns whole
    // window-rows; px (pair column) is the innermost sweep per XCD so the
    // two pairs sharing a 128B line are consecutive blocks on one XCD.
    const int bid  = blockIdx.x;
    const int xcd  = bid & 7;
    const int jb   = bid >> 3;            // 0..255
    const int px   = jb & 15;             // pair column, 16 floats wide
    const int grow = (jb >> 4) * 8 + xcd; // 0..127 global window-row id
    const int bimg = grow >> 5;
    const int ny   = grow & 31;
    const int hb = ny * 8, wb = px * 16;
    const float* xb = x   + (size_t)bimg * CC * HW;
    float*       ob = out + (size_t)bimg * CC * HW;

    short* xsw = xs + win * 16384;
    short* qkw = qk + win * 4096;

    const f32x4 zero4 = {0.f, 0.f, 0.f, 0.f};

    // ---- phase 1: global x -> LDS bf16 X^T[p][c] per window, zero-padded.
    // Pair row = 16 floats = one full 64B line (2 lanes x float4).
    // Each thread: 4 iterations x (4 float4 channel loads -> 4 b64 writes).
    {
        int s = tid & 31, cg = tid >> 5;      // s: h(3)|w4(2) slot, cg: c/4
        int hl = s >> 2, w4 = s & 3;
        int wn = w4 >> 1;                     // which window of the pair
        int p0 = hl * 8 + (w4 & 1) * 4;
        int hg = hb + hl, w0 = wb + w4 * 4;
        bool inb = (hg < HH) && (w0 < WW);    // edge float4s fully OOB, never partial
        const float* src = xb + (size_t)hg * WW + w0;
        short* dst = xs + wn * 16384;
        #pragma unroll
        for (int it = 0; it < 4; ++it) {
            int c0 = it * 64 + cg * 4;
            float4 f[4];
            #pragma unroll
            for (int k = 0; k < 4; ++k) {
                if (inb) f[k] = *reinterpret_cast<const float4*>(src + (size_t)(c0 + k) * HW);
                else     f[k] = make_float4(0.f, 0.f, 0.f, 0.f);
            }
            #pragma unroll
            for (int i = 0; i < 4; ++i) {
                uint2 w2;
                w2.x = pk2(((const float*)&f[0])[i], ((const float*)&f[1])[i]);
                w2.y = pk2(((const float*)&f[2])[i], ((const float*)&f[3])[i]);
                *reinterpret_cast<uint2*>(&dst[xaddr(p0 + i, c0)]) = w2;
            }
        }
    }
    __syncthreads();

    // ---- phase 2a: Q/K GEMM (per window). wvv 0,1 -> Q; 2,3 -> K.
    // X is the B-operand. Only 16 acc regs live (R4 spill fix: keep unfused).
    {
        const bool isK = (wvv >> 1) != 0;
        const int mt = wvv & 1;
        const short* WFqk = wf + (isK ? 8192 : 0);
        f32x4 qacc[4];
        #pragma unroll
        for (int nt = 0; nt < 4; ++nt) qacc[nt] = zero4;
        #pragma unroll
        for (int kt = 0; kt < 8; ++kt) {
            bf8 aw = *reinterpret_cast<const bf8*>(
                WFqk + ((mt * 8 + kt) * 64 + lane) * 8);
            #pragma unroll
            for (int nt = 0; nt < 4; ++nt) {
                bf8 b = *reinterpret_cast<const bf8*>(
                    &xsw[xaddr(nt * 16 + l15, kt * 32 + quad * 8)]);
                qacc[nt] = __builtin_amdgcn_mfma_f32_16x16x32_bf16(
                    aw, b, qacc[nt], 0, 0, 0);
            }
        }
        int cb = mt * 16 + quad * 4;
        const float* bias = isK ? bk : bq;
        float bi0 = bias[cb + 0], bi1 = bias[cb + 1];
        float bi2 = bias[cb + 2], bi3 = bias[cb + 3];
        short* dst = isK ? (qkw + 2048) : qkw;
        #pragma unroll
        for (int nt = 0; nt < 4; ++nt) {
            int pos = nt * 16 + l15;
            uint2 w2;
            w2.x = pk2(qacc[nt][0] + bi0, qacc[nt][1] + bi1);
            w2.y = pk2(qacc[nt][2] + bi2, qacc[nt][3] + bi3);
            *reinterpret_cast<uint2*>(&dst[qaddr(pos, cb)]) = w2;
        }
    }

    // ---- phase 2b: transposed V GEMM  V^T[p][c] = X^T[p][cin] * Wv^T[cin][c]
    // (X as A-operand). 64 acc regs live, fits the 128-reg budget, no spill.
    f32x4 vacc[4][4];                       // [p-tile][c-tile within wave]
    #pragma unroll
    for (int t = 0; t < 4; ++t)
        #pragma unroll
        for (int ni = 0; ni < 4; ++ni) vacc[t][ni] = zero4;
    {
        #pragma unroll
        for (int kt = 0; kt < 8; ++kt) {
            bf8 xfr[4];
            #pragma unroll
            for (int t = 0; t < 4; ++t)
                xfr[t] = *reinterpret_cast<const bf8*>(
                    &xsw[xaddr(t * 16 + l15, kt * 32 + quad * 8)]);
            #pragma unroll
            for (int ni = 0; ni < 4; ++ni) {
                bf8 bw = *reinterpret_cast<const bf8*>(
                    wf + 16384 + (((wvv * 4 + ni) * 8 + kt) * 64 + lane) * 8);
                #pragma unroll
                for (int t = 0; t < 4; ++t)
                    vacc[t][ni] = __builtin_amdgcn_mfma_f32_16x16x32_bf16(
                        xfr[t], bw, vacc[t][ni], 0, 0, 0);
            }
        }
    }
    __syncthreads();   // all X reads done; qs/ks visible to everyone

    // ---- write V (+bias, bf16) into xsw as V[c][p]: contiguous b64 writes.
    #pragma unroll
    for (int ni = 0; ni < 4; ++ni) {
        int c = wvv * 64 + ni * 16 + l15;
        float bvc = bv[c];
        #pragma unroll
        for (int t = 0; t < 4; ++t) {
            int p = t * 16 + quad * 4;
            uint2 w2;
            w2.x = pk2(vacc[t][ni][0] + bvc, vacc[t][ni][1] + bvc);
            w2.y = pk2(vacc[t][ni][2] + bvc, vacc[t][ni][3] + bvc);
            *reinterpret_cast<uint2*>(&xsw[vaddr(c, p)]) = w2;
        }
    }
    // S-phase operands must be read BEFORE ps overwrites qs/ks (aliased).
    bf8 aq = *reinterpret_cast<const bf8*>(&qkw[qaddr(wvv * 16 + l15, quad * 8)]);
    bf8 kb8[4];
    #pragma unroll
    for (int nt = 0; nt < 4; ++nt)
        kb8[nt] = *reinterpret_cast<const bf8*>(
            &qkw[2048 + qaddr(nt * 16 + l15, quad * 8)]);
    __syncthreads();   // qs/ks reads done -> ps may alias; V visible

    // ---- S = q^T k (M=i, N=j, K=32), softmax rows, P -> LDS bf16 (in qkw)
    {
        f32x4 sacc[4];
        #pragma unroll
        for (int nt = 0; nt < 4; ++nt)
            sacc[nt] = __builtin_amdgcn_mfma_f32_16x16x32_bf16(
                aq, kb8[nt], zero4, 0, 0, 0);
        #pragma unroll
        for (int r = 0; r < 4; ++r) {
            float mx = fmaxf(fmaxf(sacc[0][r], sacc[1][r]),
                             fmaxf(sacc[2][r], sacc[3][r]));
            for (int m = 1; m < 16; m <<= 1) mx = fmaxf(mx, __shfl_xor(mx, m, 64));
            float e0 = __expf(sacc[0][r] - mx);
            float e1 = __expf(sacc[1][r] - mx);
            float e2 = __expf(sacc[2][r] - mx);
            float e3 = __expf(sacc[3][r] - mx);
            float sum = e0 + e1 + e2 + e3;
            for (int m = 1; m < 16; m <<= 1) sum += __shfl_xor(sum, m, 64);
            float inv = 1.f / sum;
            int i = wvv * 16 + quad * 4 + r;
            qkw[paddr(i,  0 + l15)] = f2bf(e0 * inv);
            qkw[paddr(i, 16 + l15)] = f2bf(e1 * inv);
            qkw[paddr(i, 32 + l15)] = f2bf(e2 * inv);
            qkw[paddr(i, 48 + l15)] = f2bf(e3 * inv);
        }
    }
    __syncthreads();   // V + P ready

    // ---- O = V P^T (M=c 256, N=i 64, K=j 64). wave owns c in [64wvv,+64).
    f32x4 oacc[4][4];
    #pragma unroll
    for (int mi = 0; mi < 4; ++mi)
        #pragma unroll
        for (int nt = 0; nt < 4; ++nt) oacc[mi][nt] = zero4;
    #pragma unroll
    for (int kt = 0; kt < 2; ++kt) {
        bf8 av[4], bp[4];
        #pragma unroll
        for (int mi = 0; mi < 4; ++mi)
            av[mi] = *reinterpret_cast<const bf8*>(
                &xsw[vaddr((wvv * 4 + mi) * 16 + l15, kt * 32 + quad * 8)]);
        #pragma unroll
        for (int nt = 0; nt < 4; ++nt)
            bp[nt] = *reinterpret_cast<const bf8*>(
                &qkw[paddr(nt * 16 + l15, kt * 32 + quad * 8)]);
        #pragma unroll
        for (int nt = 0; nt < 4; ++nt)
            #pragma unroll
            for (int mi = 0; mi < 4; ++mi)
                oacc[mi][nt] = __builtin_amdgcn_mfma_f32_16x16x32_bf16(
                    av[mi], bp[nt], oacc[mi][nt], 0, 0, 0);
    }
    __syncthreads();   // all V/P reads done -> xs reusable as f32 O-stage

    // ---- epilogue: stage O (f32) in xs, then coalesced float4 RMW.
    // Two half-passes over channels: half h covers c in [128h, 128h+128).
    // Stage layout [c 0..127][P 0..127], P = win*64 + pos. The pair row is
    // 16 floats = a full 64B line; lanes are consecutive along P -> dense.
    float* st = (float*)xs;
    float g = gamma[0];
    #pragma unroll
    for (int Hh = 0; Hh < 2; ++Hh) {
        if ((wvv >> 1) == Hh) {            // wave-uniform branch
            #pragma unroll
            for (int mi = 0; mi < 4; ++mi) {
                int cl = (wvv & 1) * 64 + mi * 16 + quad * 4;
                #pragma unroll
                for (int nt = 0; nt < 4; ++nt) {
                    int P = win * 64 + nt * 16 + l15;
                    #pragma unroll
                    for (int r = 0; r < 4; ++r)
                        st[saddr(cl + r, P)] = oacc[mi][nt][r];
                }
            }
        }
        __syncthreads();                   // half staged
        #pragma unroll
        for (int i = 0; i < 8; ++i) {
            int idx = i * 512 + tid;
            int c = idx >> 5, p4 = idx & 31;
            int P = p4 * 4;
            int wn = P >> 6, pos = P & 63;
            int hg = hb + (pos >> 3), wg = wb + wn * 8 + (pos & 7);
            if (hg < HH && wg < WW) {      // edge float4s fully OOB, never partial
                size_t o = (size_t)(Hh * 128 + c) * HW + (size_t)hg * WW + wg;
                float4 xv = *reinterpret_cast<const float4*>(xb + o);
                f32x4 sv = *reinterpret_cast<const f32x4*>(&st[saddr(c, P)]);
                float4 ov;
                ov.x = g * sv[0] + xv.x;
                ov.y = g * sv[1] + xv.y;
                ov.z = g * sv[2] + xv.z;
                ov.w = g * sv[3] + xv.w;
                *reinterpret_cast<float4*>(ob + o) = ov;
            }
        }
        __syncthreads();                   // half consumed; st reusable
    }
}

extern "C" void kernel_launch(void* const* d_in, const int* in_sizes, int n_in,
                              void* d_out, int out_size, void* d_ws, size_t ws_size,
                              hipStream_t stream) {
    const float* x  = (const float*)d_in[0];
    const float* Wq = (const float*)d_in[1];
    const float* bq = (const float*)d_in[2];
    const float* Wk = (const float*)d_in[3];
    const float* bk = (const float*)d_in[4];
    const float* Wv = (const float*)d_in[5];
    const float* bv = (const float*)d_in[6];
    const float* gm = (const float*)d_in[7];
    short* wf = (short*)d_ws;   // 163840 B of bf16 weight fragments

    prep_weights<<<320, 256, 0, stream>>>(Wq, Wk, Wv, wf);
    area_attn<<<2048, 512, 0, stream>>>(x, wf, bq, bk, bv, gm, (float*)d_out);
}